// Round 3
// baseline (206.561 us; speedup 1.0000x reference)
//
#include <hip/hip_runtime.h>

// Problem constants (match reference): B=8, H=32, T=2048, D=128, S=512, fp32.
// N = B*H*T*D = 2^26 floats per cache. All power-of-two -> shift/mask indexing.
constexpr int B = 8;
constexpr int H = 32;
constexpr int T = 2048;
constexpr int D = 128;
constexpr int S = 512;
constexpr long long N  = (long long)B * H * T * D;   // 67,108,864 floats
constexpr long long N4 = N / 4;                      // 16,777,216 float4 per cache

typedef float f4 __attribute__((ext_vector_type(4)));

// Each block owns a contiguous CHUNK of float4 slots of ONE tensor (K or V):
// one read stream -> one write stream, memcpy-like. b,h are block-uniform
// (T*D/4 = 65536 float4 per (b,h); CHUNK=4096 divides it).
constexpr int CHUNK = 4096;                           // float4 per block
constexpr int NBLK  = (int)(N4 / CHUNK);              // 4096 blocks per tensor

__global__ __launch_bounds__(256) void kv_append_kernel(
    const f4* __restrict__ kc, const f4* __restrict__ vc,
    const int* __restrict__ pos,
    const f4* __restrict__ kv, const f4* __restrict__ vv,
    f4*       __restrict__ out)
{
    int bid = blockIdx.x;
    const f4* cache; const f4* val; f4* dst;
    if (bid < NBLK) {                 // K half
        cache = kc; val = kv; dst = out;
    } else {                          // V half
        bid -= NBLK; cache = vc; val = vv; dst = out + N4;
    }

    const long long base = (long long)bid * CHUNK;
    // b = floor(i / 2^21), h = (i >> 16) & 31  (float4 units) — block-uniform.
    const int b = __builtin_amdgcn_readfirstlane((int)(base >> 21));
    const int h = __builtin_amdgcn_readfirstlane((int)((base >> 16) & (H - 1)));
    const int p = pos[b];                              // scalar (s_load) path
    const long long vbase = (((long long)b * H + h) * S) * (D / 4);

    #pragma unroll 8
    for (int it = 0; it < CHUNK / 256; ++it) {
        const long long i = base + it * 256 + threadIdx.x;
        const int t = (int)((i >> 5) & (T - 1));       // row within [0,T)
        const int s = t - p;
        const bool ins = (unsigned)s < (unsigned)S;    // inside appended slice?
        const long long d4 = i & (D / 4 - 1);
        const long long vi = vbase + (long long)s * (D / 4) + d4;

        // Pointer select (v_cndmask on address) — no divergent branch.
        const f4* src = ins ? (val + vi) : (cache + i);
        f4 r = __builtin_nontemporal_load(src);
        __builtin_nontemporal_store(r, dst + i);
    }

    // new_pos (output 2): B float values at the tail of d_out (fused; one
    // block only, deterministic).
    if (blockIdx.x == 2 * NBLK - 1 && threadIdx.x < B) {
        float* out_pos = (float*)(out + 2 * N4);
        out_pos[threadIdx.x] = (float)(pos[threadIdx.x] + S);
    }
}

extern "C" void kernel_launch(void* const* d_in, const int* in_sizes, int n_in,
                              void* d_out, int out_size, void* d_ws, size_t ws_size,
                              hipStream_t stream) {
    (void)in_sizes; (void)n_in; (void)d_ws; (void)ws_size; (void)out_size;

    const f4*  kc  = (const f4*)d_in[0];  // k_cache [B,H,T,D]
    const f4*  vc  = (const f4*)d_in[1];  // v_cache [B,H,T,D]
    const int* pos = (const int*)d_in[2]; // current_pos [B]
    const f4*  kv  = (const f4*)d_in[3];  // k_val [B,H,S,D]
    const f4*  vv  = (const f4*)d_in[4];  // v_val [B,H,S,D]

    f4* out = (f4*)d_out;

    kv_append_kernel<<<dim3(2 * NBLK), dim3(256), 0, stream>>>(kc, vc, pos, kv, vv, out);
}

// Round 4
// 200.938 us; speedup vs baseline: 1.0280x; 1.0280x over previous
//
#include <hip/hip_runtime.h>

// Problem constants (match reference): B=8, H=32, T=2048, D=128, S=512, fp32.
// N = B*H*T*D = 2^26 floats per cache. All power-of-two -> shift/mask indexing.
constexpr int B = 8;
constexpr int H = 32;
constexpr int T = 2048;
constexpr int D = 128;
constexpr int S = 512;
constexpr long long N  = (long long)B * H * T * D;   // 67,108,864 floats
constexpr long long N4 = N / 4;                      // 16,777,216 float4 per cache

typedef float f4 __attribute__((ext_vector_type(4)));

constexpr int D4    = D / 4;                          // 32 f4 per row
constexpr int CHUNK = 4096;                           // f4 per block (=128 rows)
constexpr int RPB   = CHUNK / D4;                     // 128 rows per block
constexpr int NBLK  = (int)(N4 / CHUNK);              // 4096 blocks per tensor

// Pure streaming copy: 8 loads batched, one vmcnt drain, 8 stores. This is
// the m13-copy inner loop — no per-element source selection.
__device__ __forceinline__ void seg_copy(f4* __restrict__ dst,
                                         const f4* __restrict__ src, int n)
{
    int j = (int)threadIdx.x;
    for (; j + 7 * 256 < n; j += 8 * 256) {
        f4 r[8];
        #pragma unroll
        for (int u = 0; u < 8; ++u) r[u] = __builtin_nontemporal_load(src + j + u * 256);
        #pragma unroll
        for (int u = 0; u < 8; ++u) __builtin_nontemporal_store(r[u], dst + j + u * 256);
    }
    for (; j < n; j += 256)
        __builtin_nontemporal_store(__builtin_nontemporal_load(src + j), dst + j);
}

// Each block owns 128 consecutive rows of one tensor (K or V). The slice
// [p, p+S) cuts those rows into <=3 contiguous segments; each segment is a
// contiguous memcpy in BOTH source and destination (val rows r in [c0,c1)
// map to contiguous val rows r-p). Segment math is scalar, once per block.
__global__ __launch_bounds__(256) void kv_append_kernel(
    const f4* __restrict__ kc, const f4* __restrict__ vc,
    const int* __restrict__ pos,
    const f4* __restrict__ kv, const f4* __restrict__ vv,
    f4*       __restrict__ out)
{
    int bid = blockIdx.x;
    const f4* cache; const f4* val; f4* dst;
    if (bid < NBLK) {                 // K half
        cache = kc; val = kv; dst = out;
    } else {                          // V half
        bid -= NBLK; cache = vc; val = vv; dst = out + N4;
    }

    const long long base = (long long)bid * CHUNK;    // f4 offset in tensor
    const int b  = (int)(base >> 21);                 // 2^21 f4 per batch
    const int h  = (int)((base >> 16) & (H - 1));     // 2^16 f4 per head
    const int t0 = (int)((base >> 5) & (T - 1));      // 32 f4 per row
    const int p  = __builtin_amdgcn_readfirstlane(pos[b]);

    // Clamp slice bounds into this block's row range [t0, t0+RPB).
    int c0 = min(max(p,     t0), t0 + RPB);
    int c1 = min(max(p + S, t0), t0 + RPB);

    const int nA = (c0 - t0) * D4;                    // cache rows before slice
    const int nB = (c1 - c0) * D4;                    // val rows
    const int nC = (t0 + RPB - c1) * D4;              // cache rows after slice

    const long long vbase = (((long long)b * H + h) * S) * D4;

    seg_copy(dst + base,           cache + base,           nA);
    seg_copy(dst + base + nA,      val + vbase + (long long)(c0 - p) * D4, nB);
    seg_copy(dst + base + nA + nB, cache + base + nA + nB, nC);

    // new_pos (output 2): B float values at the tail of d_out (fused).
    if (blockIdx.x == 2 * NBLK - 1 && threadIdx.x < B) {
        float* out_pos = (float*)(out + 2 * N4);
        out_pos[threadIdx.x] = (float)(pos[threadIdx.x] + S);
    }
}

extern "C" void kernel_launch(void* const* d_in, const int* in_sizes, int n_in,
                              void* d_out, int out_size, void* d_ws, size_t ws_size,
                              hipStream_t stream) {
    (void)in_sizes; (void)n_in; (void)d_ws; (void)ws_size; (void)out_size;

    const f4*  kc  = (const f4*)d_in[0];  // k_cache [B,H,T,D]
    const f4*  vc  = (const f4*)d_in[1];  // v_cache [B,H,T,D]
    const int* pos = (const int*)d_in[2]; // current_pos [B]
    const f4*  kv  = (const f4*)d_in[3];  // k_val [B,H,S,D]
    const f4*  vv  = (const f4*)d_in[4];  // v_val [B,H,S,D]

    f4* out = (f4*)d_out;

    kv_append_kernel<<<dim3(2 * NBLK), dim3(256), 0, stream>>>(kc, vc, pos, kv, vv, out);
}